// Round 10
// baseline (215.139 us; speedup 1.0000x reference)
//
#include <hip/hip_runtime.h>

#define THRESH 0.7f
#define ROWS 4   // elements per thread, wave-strided (lane-contiguous rows)

typedef float nfloat2 __attribute__((ext_vector_type(2)));
typedef float nfloat4 __attribute__((ext_vector_type(4)));

__device__ __forceinline__ float2 nt_load2(const float2* p) {
    nfloat2 v = __builtin_nontemporal_load(reinterpret_cast<const nfloat2*>(p));
    return make_float2(v.x, v.y);
}

__device__ __forceinline__ float4 nt_load4(const float4* p) {
    nfloat4 v = __builtin_nontemporal_load(reinterpret_cast<const nfloat4*>(p));
    return make_float4(v.x, v.y, v.z, v.w);
}

// Winner so far (r7/r9): scalar nt-loads + cached stores, <=58 us.
// This round: wave-strided ILP. Block owns 1024 consecutive elements as 4
// rows of 256; every instruction stays wave-contiguous (the r8 failure was
// 64B/lane stride, NOT vectorization per se). All loads issue before any
// consumption: 4x cls + up to 8 predicated box loads in flight per wave,
// 1/4 the waves. Predicated box loads kept (neutral in time, saves ~24% of
// box lines). Stores cached (r1: nt stores = 2x write amplification).
__global__ __launch_bounds__(256) void rnet_post_nt_ilp(
    const float2* __restrict__ cls,    // [M] (bg, face)
    const float4* __restrict__ reg,    // [M]
    const float4* __restrict__ rects,  // [M]
    const int*    __restrict__ hptr,
    const int*    __restrict__ wptr,
    float4* __restrict__ out_rects,    // [M]
    float*  __restrict__ out_scores,   // [M]
    float*  __restrict__ out_keep,     // [M]
    int M)
{
    const float fh = (float)*hptr;
    const float fw = (float)*wptr;

    int base = blockIdx.x * (256 * ROWS) + threadIdx.x;

    float2 c[ROWS];
    float4 r[ROWS], d[ROWS];
    bool   k[ROWS];
    bool   inb[ROWS];

    // Pass 1: issue all cls loads (wave-contiguous 8B/lane).
#pragma unroll
    for (int q = 0; q < ROWS; ++q) {
        int i = base + q * 256;
        inb[q] = (i < M);
        c[q] = inb[q] ? nt_load2(&cls[i]) : make_float2(0.0f, 0.0f);
    }

    // Pass 2: issue all predicated box loads (exec-masked; no consumption yet).
#pragma unroll
    for (int q = 0; q < ROWS; ++q) {
        int i = base + q * 256;
        k[q] = inb[q] && (c[q].y > THRESH);
        if (k[q]) {
            r[q] = nt_load4(&rects[i]);
            d[q] = nt_load4(&reg[i]);
        }
    }

    // Pass 3: compute + store.
#pragma unroll
    for (int q = 0; q < ROWS; ++q) {
        int i = base + q * 256;
        if (!inb[q]) continue;

        float4 o = make_float4(0.0f, 0.0f, 0.0f, 0.0f);
        float s = 0.0f, kf = 0.0f;
        if (k[q]) {
            float w = r[q].z - r[q].x;
            float h = r[q].w - r[q].y;
            o.x = fminf(fmaxf(fmaf(d[q].x, w, r[q].x), 0.0f), fw);
            o.y = fminf(fmaxf(fmaf(d[q].y, h, r[q].y), 0.0f), fh);
            o.z = fminf(fmaxf(fmaf(d[q].z, w, r[q].z), 0.0f), fw);
            o.w = fminf(fmaxf(fmaf(d[q].w, h, r[q].w), 0.0f), fh);
            s = c[q].y;
            kf = 1.0f;
        }
        out_rects[i]  = o;
        out_scores[i] = s;
        out_keep[i]   = kf;
    }
}

extern "C" void kernel_launch(void* const* d_in, const int* in_sizes, int n_in,
                              void* d_out, int out_size, void* d_ws, size_t ws_size,
                              hipStream_t stream) {
    const float2* cls   = (const float2*)d_in[0];  // classifier [B,N,2]
    const float4* reg   = (const float4*)d_in[1];  // bbox_regress [B,N,4]
    const float4* rects = (const float4*)d_in[2];  // input_rects [B,N,4]
    const int*    hptr  = (const int*)d_in[3];     // input_height scalar
    const int*    wptr  = (const int*)d_in[4];     // input_width scalar

    const int M = in_sizes[0] / 2;  // B*N

    float* out = (float*)d_out;
    float4* out_rects  = (float4*)out;        // 4*M floats
    float*  out_scores = out + 4ll * M;       // M floats
    float*  out_keep   = out + 5ll * M;       // M floats

    const int block = 256;
    const int elems_per_block = block * ROWS;
    const int grid = (M + elems_per_block - 1) / elems_per_block;
    rnet_post_nt_ilp<<<grid, block, 0, stream>>>(cls, reg, rects, hptr, wptr,
                                                 out_rects, out_scores, out_keep, M);
}